// Round 1
// baseline (321.112 us; speedup 1.0000x reference)
//
#include <hip/hip_runtime.h>

// RGCN block: B=512, C=256, R=8, N=81 (9x9), fp32 in/out, bf16 MFMA compute.
//
// out_h[b,n,d] = sum_r (adj[b,r] @ h[b]) @ W[r],  h[b][m][c] = x[b][c][m]
// pre = out_h^T + x ; BN(train, biased) over (B,N) per channel ; *gamma+beta ; relu

#define B_SZ 512
#define C_SZ 256
#define R_SZ 8
#define N_SZ 81
#define NP 96          // N padded to multiple of 32 (K for stage 1)
#define TH 512         // threads per block in main kernel

typedef short bf16x8 __attribute__((ext_vector_type(8)));
typedef float f32x4 __attribute__((ext_vector_type(4)));

__device__ __forceinline__ unsigned short f2bf(float f) {
    union { float f; unsigned u; } v; v.f = f;
    unsigned r = v.u + 0x7FFFu + ((v.u >> 16) & 1u);   // RNE
    return (unsigned short)(r >> 16);
}

// ---- kernel 0: weight (R,C,C) fp32 -> WT[r][d][c] bf16 ----
__global__ void prep_wt(const float* __restrict__ w, unsigned short* __restrict__ wt) {
    int i = blockIdx.x * blockDim.x + threadIdx.x;
    if (i >= R_SZ * C_SZ * C_SZ) return;
    int r = i >> 16;
    int d = (i >> 8) & 255;
    int c = i & 255;
    wt[i] = f2bf(w[(r * C_SZ + c) * C_SZ + d]);   // wt layout [r][d][c], coalesced write
}

// ---- kernel 1: fused RGCN per batch ----
// grid 512 blocks x 512 threads (8 waves as 2 row x 4 col)
__launch_bounds__(TH, 2)
__global__ void rgcn_main(const float* __restrict__ x,
                          const float* __restrict__ adj,
                          const unsigned short* __restrict__ wt,
                          float* __restrict__ out,
                          float* __restrict__ psum) {
    __shared__ unsigned short hT[256][104];    // h^T: [c][m], m padded 81->104 (53248 B)
    __shared__ unsigned short adjs[96][104];   // adj_r [n][m] (19968 B)
    __shared__ unsigned short msgs[96][264];   // msg [n][c], c padded 256->264 (50688 B)

    const int b    = blockIdx.x;
    const int tid  = threadIdx.x;
    const int lane = tid & 63;
    const int wave = tid >> 6;
    const int wrow = wave >> 2;     // 0..1  -> 48 output rows each
    const int wcol = wave & 3;      // 0..3  -> 64 output cols each
    const int lr   = lane & 15;     // fragment row (A) / col (B,D)
    const int lk   = lane >> 4;     // k-chunk 0..3

    const float* xb = x + (size_t)b * C_SZ * N_SZ;

    // load h^T from x[b] (already [c][m] layout), pad m 81..103 with 0
    for (int i = tid; i < 256 * 104; i += TH) {
        int c = i / 104, m = i - c * 104;
        hT[c][m] = (m < N_SZ) ? f2bf(xb[c * N_SZ + m]) : (unsigned short)0;
    }
    // zero adj tile once (pads n>=81 / m>=81 persist as zero)
    for (int i = tid; i < 96 * 104; i += TH) {
        adjs[i / 104][i % 104] = 0;
    }
    __syncthreads();

    f32x4 acc[3][4];
    const f32x4 vzero = {0.f, 0.f, 0.f, 0.f};
#pragma unroll
    for (int i = 0; i < 3; ++i)
#pragma unroll
        for (int j = 0; j < 4; ++j) acc[i][j] = vzero;

    const float* adjb = adj + (size_t)b * R_SZ * N_SZ * N_SZ;

    for (int r = 0; r < R_SZ; ++r) {
        // ---- load adj_r (fp32 -> bf16) ----
        const float* ar = adjb + r * (N_SZ * N_SZ);
        for (int i = tid; i < N_SZ * N_SZ; i += TH) {
            int n = i / N_SZ, m = i - n * N_SZ;
            adjs[n][m] = f2bf(ar[i]);
        }
        __syncthreads();   // adj ready (also: all waves done with prev stage2 msg reads)

        // ---- stage 1: msg = adj_r @ h   (96 x 256, K=96) ----
        f32x4 macc[3][4];
#pragma unroll
        for (int i = 0; i < 3; ++i)
#pragma unroll
            for (int j = 0; j < 4; ++j) macc[i][j] = vzero;

#pragma unroll
        for (int kk = 0; kk < 3; ++kk) {
            bf16x8 afr[3], bfr[4];
#pragma unroll
            for (int i = 0; i < 3; ++i) {
                int row = wrow * 48 + i * 16 + lr;
                afr[i] = *(const bf16x8*)&adjs[row][kk * 32 + lk * 8];
            }
#pragma unroll
            for (int j = 0; j < 4; ++j) {
                int col = wcol * 64 + j * 16 + lr;
                bfr[j] = *(const bf16x8*)&hT[col][kk * 32 + lk * 8];
            }
#pragma unroll
            for (int i = 0; i < 3; ++i)
#pragma unroll
                for (int j = 0; j < 4; ++j)
                    macc[i][j] = __builtin_amdgcn_mfma_f32_16x16x32_bf16(afr[i], bfr[j], macc[i][j], 0, 0, 0);
        }

        // write msg to LDS as bf16 (D layout: col=lane&15, row=(lane>>4)*4+reg)
#pragma unroll
        for (int i = 0; i < 3; ++i) {
            int rowb = wrow * 48 + i * 16 + lk * 4;
#pragma unroll
            for (int j = 0; j < 4; ++j) {
                int col = wcol * 64 + j * 16 + lr;
#pragma unroll
                for (int q = 0; q < 4; ++q)
                    msgs[rowb + q][col] = f2bf(macc[i][j][q]);
            }
        }
        __syncthreads();   // msg ready

        // ---- stage 2: acc += msg @ W_r  (K=256), B streamed from L2-resident WT ----
        const unsigned short* wr = wt + r * (C_SZ * C_SZ);
#pragma unroll
        for (int kk = 0; kk < 8; ++kk) {
            bf16x8 afr[3], bfr[4];
#pragma unroll
            for (int i = 0; i < 3; ++i) {
                int row = wrow * 48 + i * 16 + lr;
                afr[i] = *(const bf16x8*)&msgs[row][kk * 32 + lk * 8];
            }
#pragma unroll
            for (int j = 0; j < 4; ++j) {
                int col = wcol * 64 + j * 16 + lr;               // channel d
                bfr[j] = *(const bf16x8*)&wr[col * 256 + kk * 32 + lk * 8];
            }
#pragma unroll
            for (int i = 0; i < 3; ++i)
#pragma unroll
                for (int j = 0; j < 4; ++j)
                    acc[i][j] = __builtin_amdgcn_mfma_f32_16x16x32_bf16(afr[i], bfr[j], acc[i][j], 0, 0, 0);
        }
        // no barrier needed here: next adj-ready barrier orders msg reads vs next msg writes
    }

    // ---- epilogue: pre = out_h^T + x, write out, per-block channel sums ----
    float* red = (float*)&adjs[0][0];          // reuse adj tile: red[0..255]=sum, [256..511]=sumsq
    red[tid < 512 ? tid : 0] = 0.f;            // each of 512 threads zeroes one slot
    if (tid < 512) red[tid] = 0.f;

    float s1[4] = {0.f, 0.f, 0.f, 0.f};
    float s2[4] = {0.f, 0.f, 0.f, 0.f};
    float* outb = out + (size_t)b * C_SZ * N_SZ;
#pragma unroll
    for (int i = 0; i < 3; ++i) {
#pragma unroll
        for (int j = 0; j < 4; ++j) {
            int d = wcol * 64 + j * 16 + lr;
#pragma unroll
            for (int q = 0; q < 4; ++q) {
                int n = wrow * 48 + i * 16 + lk * 4 + q;
                if (n < N_SZ) {
                    float pre = acc[i][j][q] + xb[d * N_SZ + n];
                    outb[d * N_SZ + n] = pre;
                    s1[j] += pre;
                    s2[j] += pre * pre;
                }
            }
        }
    }
    __syncthreads();   // red zeroed before atomics; stage2 readers done (program order per wave)
#pragma unroll
    for (int j = 0; j < 4; ++j) {
        int d = wcol * 64 + j * 16 + lr;
        atomicAdd(&red[d], s1[j]);
        atomicAdd(&red[256 + d], s2[j]);
    }
    __syncthreads();
    if (tid < 256) {
        psum[(size_t)b * 256 + tid] = red[tid];
        psum[(size_t)B_SZ * 256 + (size_t)b * 256 + tid] = red[256 + tid];
    }
}

// ---- kernel 2: reduce per-block partials -> mean, rstd per channel ----
__global__ void bn_stats(const float* __restrict__ psum, float* __restrict__ mr) {
    int c = threadIdx.x;   // 256 threads, 1 block
    float s1 = 0.f, s2 = 0.f;
    for (int b = 0; b < B_SZ; ++b) {
        s1 += psum[(size_t)b * 256 + c];
        s2 += psum[(size_t)B_SZ * 256 + (size_t)b * 256 + c];
    }
    const float inv = 1.0f / (float)(B_SZ * N_SZ);
    float mean = s1 * inv;
    float var = s2 * inv - mean * mean;
    mr[c] = mean;
    mr[256 + c] = rsqrtf(var + 1e-5f);
}

// ---- kernel 3: normalize + gamma/beta + relu, in place on out ----
__global__ void bn_apply(float* __restrict__ out, const float* __restrict__ mr,
                         const float* __restrict__ gamma, const float* __restrict__ beta) {
    const int total = B_SZ * C_SZ * N_SZ;
    for (int i = blockIdx.x * blockDim.x + threadIdx.x; i < total;
         i += gridDim.x * blockDim.x) {
        int c = (i / N_SZ) & 255;
        float v = out[i];
        v = (v - mr[c]) * mr[256 + c] * gamma[c] + beta[c];
        out[i] = v > 0.f ? v : 0.f;
    }
}

extern "C" void kernel_launch(void* const* d_in, const int* in_sizes, int n_in,
                              void* d_out, int out_size, void* d_ws, size_t ws_size,
                              hipStream_t stream) {
    const float* x     = (const float*)d_in[0];
    const float* adj   = (const float*)d_in[1];
    const float* w     = (const float*)d_in[2];
    const float* gamma = (const float*)d_in[3];
    const float* beta  = (const float*)d_in[4];
    float* out = (float*)d_out;

    // workspace layout
    unsigned short* wt = (unsigned short*)d_ws;                              // 1 MB
    char* p = (char*)d_ws + (size_t)R_SZ * C_SZ * C_SZ * 2;
    float* psum = (float*)p;                                                 // 1 MB
    float* mr = (float*)(p + (size_t)2 * B_SZ * 256 * 4);                    // 2 KB

    prep_wt<<<(R_SZ * C_SZ * C_SZ + 255) / 256, 256, 0, stream>>>(w, wt);
    rgcn_main<<<B_SZ, TH, 0, stream>>>(x, adj, wt, out, psum);
    bn_stats<<<1, 256, 0, stream>>>(psum, mr);
    bn_apply<<<2048, 256, 0, stream>>>(out, mr, gamma, beta);
}